// Round 4
// baseline (281.976 us; speedup 1.0000x reference)
//
#include <hip/hip_runtime.h>
#include <math.h>

typedef _Float16 half8_t __attribute__((ext_vector_type(8)));
typedef _Float16 half4_t __attribute__((ext_vector_type(4)));
typedef float f32x4 __attribute__((ext_vector_type(4)));

#define MFMA16(a, b, c) __builtin_amdgcn_mfma_f32_16x16x32_f16((a), (b), (c), 0, 0, 0)

// log2(e) / sqrt(128): fold softmax scale AND exp->exp2 conversion into q.
#define SCALE_Q (0.08838834764831845f * 1.44269504088896340736f)

// ---------------------------------------------------------------------------
// Kernel 0: W [512][128] fp32  ->  Wt [128][512] fp16   (x3 for q,k,v)
// ---------------------------------------------------------------------------
__global__ __launch_bounds__(256) void wt_kernel(const float* __restrict__ Wq,
                                                 const float* __restrict__ Wk,
                                                 const float* __restrict__ Wv,
                                                 _Float16* __restrict__ WtAll) {
    int y = blockIdx.y;
    const float* W = (y == 0) ? Wq : (y == 1) ? Wk : Wv;
    int idx = blockIdx.x * 256 + threadIdx.x;
    int kk = idx >> 7;
    int d  = idx & 127;
    WtAll[y * 65536 + d * 512 + kk] = (_Float16)W[idx];
}

// ---------------------------------------------------------------------------
// Kernel 1: projection GEMM.  C[16384][128] = X[16384][512] @ W + b
// 64x128 tile, BK=64, register-prefetch pipeline. 768 blocks (3/CU).
// ---------------------------------------------------------------------------
__global__ __launch_bounds__(256, 3) void proj_kernel(
    const float* __restrict__ q_in, const float* __restrict__ k_in,
    const float* __restrict__ v_in, const _Float16* __restrict__ WtAll,
    const float* __restrict__ biasq, const float* __restrict__ biask,
    const float* __restrict__ biasv,
    _Float16* __restrict__ qbuf, _Float16* __restrict__ kbuf,
    _Float16* __restrict__ vtbuf) {
    int y = blockIdx.y;
    const float* x = (y == 0) ? q_in : (y == 1) ? k_in : v_in;
    const _Float16* Wt = WtAll + y * 65536;
    const float* bias = (y == 0) ? biasq : (y == 1) ? biask : biasv;
    int row0 = blockIdx.x * 64;

    __shared__ _Float16 smem[13824];   // 27.6 KB (staging; epilogue overlays)
    _Float16* As = smem;               // [64][72]   A tile fp16 (BK=64 +8 pad)
    _Float16* Ws = smem + 4608;        // [128][72]  W^T tile

    int tid = threadIdx.x;
    int wave = tid >> 6, lane = tid & 63, quad = lane >> 4, l16 = lane & 15;
    int wm = (wave & 1) * 32, wn = (wave >> 1) * 64;

    int arow = tid >> 2, acolf = (tid & 3) * 16;   // A stage: 64 x 64 fp32
    int wrow = tid >> 1, wcol = (tid & 1) * 32;    // W stage: 128 x 64 fp16

    const float* aptr = x + (size_t)(row0 + arow) * 512 + acolf;
    const _Float16* wptr = Wt + wrow * 512 + wcol;

    // prologue: prefetch K-step 0
    float4 a[4];
    half8_t wv[4];
    for (int i = 0; i < 4; i++) a[i] = ((const float4*)aptr)[i];
    for (int i = 0; i < 4; i++) wv[i] = *(const half8_t*)(wptr + i * 8);
    half8_t ah0, ah1;
    for (int i = 0; i < 2; i++) {
        float4 lo = a[2 * i], hi = a[2 * i + 1];
        half8_t h;
        h[0] = (_Float16)lo.x; h[1] = (_Float16)lo.y;
        h[2] = (_Float16)lo.z; h[3] = (_Float16)lo.w;
        h[4] = (_Float16)hi.x; h[5] = (_Float16)hi.y;
        h[6] = (_Float16)hi.z; h[7] = (_Float16)hi.w;
        if (i == 0) ah0 = h; else ah1 = h;
    }

    f32x4 acc[2][4] = {};

    for (int kb = 0; kb < 512; kb += 64) {
        __syncthreads();
        *(half8_t*)&As[arow * 72 + acolf]     = ah0;
        *(half8_t*)&As[arow * 72 + acolf + 8] = ah1;
        for (int i = 0; i < 4; i++)
            *(half8_t*)&Ws[wrow * 72 + wcol + i * 8] = wv[i];
        __syncthreads();

        bool more = (kb + 64) < 512;
        if (more) {
            const float* ap = aptr + kb + 64;
            const _Float16* wp = wptr + kb + 64;
            for (int i = 0; i < 4; i++) a[i] = ((const float4*)ap)[i];
            for (int i = 0; i < 4; i++) wv[i] = *(const half8_t*)(wp + i * 8);
        }

        half8_t af[2][2], bf[4][2];
        for (int mt = 0; mt < 2; mt++)
            for (int kc = 0; kc < 2; kc++)
                af[mt][kc] = *(const half8_t*)&As[(wm + mt * 16 + l16) * 72 +
                                                  kc * 32 + quad * 8];
        for (int nt = 0; nt < 4; nt++)
            for (int kc = 0; kc < 2; kc++)
                bf[nt][kc] = *(const half8_t*)&Ws[(wn + nt * 16 + l16) * 72 +
                                                  kc * 32 + quad * 8];
        for (int mt = 0; mt < 2; mt++)
            for (int nt = 0; nt < 4; nt++)
                for (int kc = 0; kc < 2; kc++)
                    acc[mt][nt] = MFMA16(af[mt][kc], bf[nt][kc], acc[mt][nt]);

        if (more) {
            for (int i = 0; i < 2; i++) {
                float4 lo = a[2 * i], hi = a[2 * i + 1];
                half8_t h;
                h[0] = (_Float16)lo.x; h[1] = (_Float16)lo.y;
                h[2] = (_Float16)lo.z; h[3] = (_Float16)lo.w;
                h[4] = (_Float16)hi.x; h[5] = (_Float16)hi.y;
                h[6] = (_Float16)hi.z; h[7] = (_Float16)hi.w;
                if (i == 0) ah0 = h; else ah1 = h;
            }
        }
    }
    __syncthreads();

    float scale = (y == 0) ? SCALE_Q : 1.0f;
    if (y < 2) {
        // row-major [s][d] tile: smem[64][136]
        for (int mt = 0; mt < 2; mt++)
            for (int nt = 0; nt < 4; nt++) {
                int d = wn + nt * 16 + l16;
                float b = bias[d];
                for (int r = 0; r < 4; r++)
                    smem[(wm + mt * 16 + quad * 4 + r) * 136 + d] =
                        (_Float16)((acc[mt][nt][r] + b) * scale);
            }
        __syncthreads();
        int orow = tid >> 2, ocol = (tid & 3) * 32;
        _Float16* outp =
            ((y == 0) ? qbuf : kbuf) + (size_t)(row0 + orow) * 128 + ocol;
        for (int i = 0; i < 4; i++)
            *(half8_t*)(outp + i * 8) =
                *(const half8_t*)&smem[orow * 136 + ocol + i * 8];
    } else {
        // transposed [d][s] tile: smem[128][72]
        for (int mt = 0; mt < 2; mt++)
            for (int nt = 0; nt < 4; nt++) {
                int d = wn + nt * 16 + l16;
                float b = bias[d];
                half4_t pk;
                for (int r = 0; r < 4; r++)
                    pk[r] = (_Float16)(acc[mt][nt][r] + b);
                *(half4_t*)&smem[d * 72 + wm + mt * 16 + quad * 4] = pk;
            }
        __syncthreads();
        int drow = tid >> 1, scol = (tid & 1) * 32;
        int bbn = row0 >> 11, s0 = row0 & 2047;
        _Float16* outp = vtbuf + ((size_t)bbn * 128 + drow) * 2048 + s0;
        for (int i = 0; i < 4; i++)
            *(half8_t*)(outp + scol + i * 8) =
                *(const half8_t*)&smem[drow * 72 + scol + i * 8];
    }
}

// ---------------------------------------------------------------------------
// Kernel 2: flash attention.  256 thr = 4 waves x 16 q = 64 q per block.
// ONLY verified 16x16x32 MFMA layouts. K staged in LDS (register prefetch);
// Q and V fragments direct from global (L2-resident). P via per-wave LDS.
// ---------------------------------------------------------------------------
__global__ __launch_bounds__(256) void attn_kernel(
    const _Float16* __restrict__ qbuf, const _Float16* __restrict__ kbuf,
    const _Float16* __restrict__ vtbuf, float* __restrict__ out) {
    int bb = blockIdx.x >> 5;
    int q0 = (blockIdx.x & 31) * 64;
    int tid = threadIdx.x, w = tid >> 6, lane = tid & 63;
    int quad = lane >> 4, l16 = lane & 15;

    __shared__ _Float16 smem[13312];          // 26.6 KB
    _Float16* Ks = smem;                      // [64][136]
    _Float16* Pt = smem + 8704 + w * 1152;    // per-wave [16][72]

    const _Float16* kbase = kbuf + (size_t)bb * 2048 * 128;
    const _Float16* vbase = vtbuf + (size_t)bb * 128 * 2048;

    // Q fragments (B operand): n=l16 -> q row = q0+w*16+l16, k=quad*8+j
    half8_t qf[4];
    {
        const _Float16* qp =
            qbuf + ((size_t)bb * 2048 + q0 + w * 16 + l16) * 128 + quad * 8;
        for (int kc = 0; kc < 4; kc++)
            qf[kc] = *(const half8_t*)(qp + kc * 32);
    }

    // K staging: 64 keys x 128 d = 8192 halfs; 256 threads -> 32 halfs each
    int krow = tid >> 2, kcol = (tid & 3) * 32;
    const _Float16* kstage = kbase + (size_t)krow * 128 + kcol;
    half8_t kr[4];
    for (int i = 0; i < 4; i++) kr[i] = *(const half8_t*)(kstage + i * 8);

    f32x4 o[8] = {};
    float m = -INFINITY, l = 0.0f;

    for (int kv = 0; kv < 2048; kv += 64) {
        __syncthreads();
        for (int i = 0; i < 4; i++)
            *(half8_t*)&Ks[krow * 136 + kcol + i * 8] = kr[i];
        __syncthreads();
        if (kv + 64 < 2048) {
            const _Float16* kp = kstage + (size_t)(kv + 64) * 128;
            for (int i = 0; i < 4; i++) kr[i] = *(const half8_t*)(kp + i * 8);
        }

        // S^T[key][q] = K Q^T : A = K rows (m=key), B = Q (n=q)
        f32x4 sf[4];
        for (int kt = 0; kt < 4; kt++) {
            f32x4 a = {0.f, 0.f, 0.f, 0.f};
            for (int kc = 0; kc < 4; kc++) {
                half8_t kf = *(const half8_t*)&Ks[(kt * 16 + l16) * 136 +
                                                  kc * 32 + quad * 8];
                a = MFMA16(kf, qf[kc], a);
            }
            sf[kt] = a;
        }

        // online softmax per q=l16; this lane's keys = kt*16 + quad*4 + r
        float mx = m;
        for (int kt = 0; kt < 4; kt++)
            for (int r = 0; r < 4; r++) mx = fmaxf(mx, sf[kt][r]);
        mx = fmaxf(mx, __shfl_xor(mx, 16, 64));
        mx = fmaxf(mx, __shfl_xor(mx, 32, 64));
        float alpha = exp2f(m - mx);
        float rs = 0.0f;
        for (int kt = 0; kt < 4; kt++) {
            half4_t pk;
            for (int r = 0; r < 4; r++) {
                float p = exp2f(sf[kt][r] - mx);
                rs += p;
                pk[r] = (_Float16)p;
            }
            *(half4_t*)&Pt[l16 * 72 + kt * 16 + quad * 4] = pk;
        }
        rs += __shfl_xor(rs, 16, 64);
        rs += __shfl_xor(rs, 32, 64);
        l = l * alpha + rs;
        m = mx;

        // rescale O: alpha of q-row quad*4+r lives at lane quad*4+r
        float ar0 = __shfl(alpha, quad * 4 + 0, 64);
        float ar1 = __shfl(alpha, quad * 4 + 1, 64);
        float ar2 = __shfl(alpha, quad * 4 + 2, 64);
        float ar3 = __shfl(alpha, quad * 4 + 3, 64);
        for (int t = 0; t < 8; t++) {
            o[t][0] *= ar0; o[t][1] *= ar1;
            o[t][2] *= ar2; o[t][3] *= ar3;
        }

        // O += P V : A = P[q][key] from LDS, B = V[key][d] direct from global
        half8_t pa0 = *(const half8_t*)&Pt[l16 * 72 + quad * 8];
        half8_t pa1 = *(const half8_t*)&Pt[l16 * 72 + 32 + quad * 8];
        const _Float16* vp = vbase + (size_t)l16 * 2048 + kv + quad * 8;
        for (int dt = 0; dt < 8; dt++) {
            const _Float16* vpd = vp + (size_t)dt * 16 * 2048;
            half8_t v0 = *(const half8_t*)(vpd);
            half8_t v1 = *(const half8_t*)(vpd + 32);
            o[dt] = MFMA16(pa0, v0, o[dt]);
            o[dt] = MFMA16(pa1, v1, o[dt]);
        }
    }

    // normalize and store (C/D: col=l16=d, row=quad*4+r=q)
    float li0 = 1.0f / __shfl(l, quad * 4 + 0, 64);
    float li1 = 1.0f / __shfl(l, quad * 4 + 1, 64);
    float li2 = 1.0f / __shfl(l, quad * 4 + 2, 64);
    float li3 = 1.0f / __shfl(l, quad * 4 + 3, 64);
    size_t srow = (size_t)bb * 2048 + q0 + w * 16 + quad * 4;
    for (int dt = 0; dt < 8; dt++) {
        int d = dt * 16 + l16;
        out[(srow + 0) * 128 + d] = o[dt][0] * li0;
        out[(srow + 1) * 128 + d] = o[dt][1] * li1;
        out[(srow + 2) * 128 + d] = o[dt][2] * li2;
        out[(srow + 3) * 128 + d] = o[dt][3] * li3;
    }
}

// ---------------------------------------------------------------------------
extern "C" void kernel_launch(void* const* d_in, const int* in_sizes, int n_in,
                              void* d_out, int out_size, void* d_ws,
                              size_t ws_size, hipStream_t stream) {
    const float* q_in = (const float*)d_in[0];
    const float* k_in = (const float*)d_in[1];
    const float* v_in = (const float*)d_in[2];
    const float* Wq = (const float*)d_in[3];
    const float* Wk = (const float*)d_in[4];
    const float* Wv = (const float*)d_in[5];
    const float* bq = (const float*)d_in[6];
    const float* bk = (const float*)d_in[7];
    const float* bv = (const float*)d_in[8];
    float* out = (float*)d_out;

    char* ws = (char*)d_ws;
    _Float16* WtAll = (_Float16*)ws;
    _Float16* qbuf  = (_Float16*)(ws + 393216);
    _Float16* kbuf  = (_Float16*)(ws + 4587520);
    _Float16* vtbuf = (_Float16*)(ws + 8781824);

    wt_kernel<<<dim3(256, 3), 256, 0, stream>>>(Wq, Wk, Wv, WtAll);
    proj_kernel<<<dim3(256, 3), 256, 0, stream>>>(q_in, k_in, v_in, WtAll, bq,
                                                  bk, bv, qbuf, kbuf, vtbuf);
    attn_kernel<<<dim3(256), 256, 0, stream>>>(qbuf, kbuf, vtbuf, out);
}

// Round 5
// 233.192 us; speedup vs baseline: 1.2092x; 1.2092x over previous
//
#include <hip/hip_runtime.h>
#include <math.h>

typedef _Float16 half8_t __attribute__((ext_vector_type(8)));
typedef _Float16 half4_t __attribute__((ext_vector_type(4)));
typedef float f32x4 __attribute__((ext_vector_type(4)));

#define MFMA16(a, b, c) __builtin_amdgcn_mfma_f32_16x16x32_f16((a), (b), (c), 0, 0, 0)

// log2(e) / sqrt(128): fold softmax scale AND exp->exp2 conversion into q.
#define SCALE_Q (0.08838834764831845f * 1.44269504088896340736f)

// ---------------------------------------------------------------------------
// Kernel 0: W [512][128] fp32  ->  Wt [128][512] fp16   (x3 for q,k,v)
// ---------------------------------------------------------------------------
__global__ __launch_bounds__(256) void wt_kernel(const float* __restrict__ Wq,
                                                 const float* __restrict__ Wk,
                                                 const float* __restrict__ Wv,
                                                 _Float16* __restrict__ WtAll) {
    int y = blockIdx.y;
    const float* W = (y == 0) ? Wq : (y == 1) ? Wk : Wv;
    int idx = blockIdx.x * 256 + threadIdx.x;
    int kk = idx >> 7;
    int d  = idx & 127;
    WtAll[y * 65536 + d * 512 + kk] = (_Float16)W[idx];
}

// ---------------------------------------------------------------------------
// Kernel 1: projection GEMM.  C[16384][128] = X[16384][512] @ W + b
// 32x128 tile, BK=64, register-prefetch. 1536 blocks (~4+/CU for latency).
// ---------------------------------------------------------------------------
__global__ __launch_bounds__(256, 4) void proj_kernel(
    const float* __restrict__ q_in, const float* __restrict__ k_in,
    const float* __restrict__ v_in, const _Float16* __restrict__ WtAll,
    const float* __restrict__ biasq, const float* __restrict__ biask,
    const float* __restrict__ biasv,
    _Float16* __restrict__ qbuf, _Float16* __restrict__ kbuf,
    _Float16* __restrict__ vtbuf) {
    int y = blockIdx.y;
    const float* x = (y == 0) ? q_in : (y == 1) ? k_in : v_in;
    const _Float16* Wt = WtAll + y * 65536;
    const float* bias = (y == 0) ? biasq : (y == 1) ? biask : biasv;
    int row0 = blockIdx.x * 32;

    __shared__ _Float16 smem[11520];   // 23 KB
    _Float16* As = smem;               // [32][72]
    _Float16* Ws = smem + 2304;        // [128][72]

    int tid = threadIdx.x;
    int wave = tid >> 6, lane = tid & 63, quad = lane >> 4, l16 = lane & 15;
    int wm = (wave & 1) * 16, wn = (wave >> 1) * 64;

    int arow = tid >> 3, acolf = (tid & 7) * 8;    // A stage: 32 x 64 fp32
    int wrow = tid >> 1, wcol = (tid & 1) * 32;    // W stage: 128 x 64 fp16

    const float* aptr = x + (size_t)(row0 + arow) * 512 + acolf;
    const _Float16* wptr = Wt + wrow * 512 + wcol;

    // prologue: prefetch K-step 0
    float4 a0 = ((const float4*)aptr)[0], a1 = ((const float4*)aptr)[1];
    half8_t wv[4];
    for (int i = 0; i < 4; i++) wv[i] = *(const half8_t*)(wptr + i * 8);
    half8_t ah;
    ah[0] = (_Float16)a0.x; ah[1] = (_Float16)a0.y;
    ah[2] = (_Float16)a0.z; ah[3] = (_Float16)a0.w;
    ah[4] = (_Float16)a1.x; ah[5] = (_Float16)a1.y;
    ah[6] = (_Float16)a1.z; ah[7] = (_Float16)a1.w;

    f32x4 acc[4] = {};

    for (int kb = 0; kb < 512; kb += 64) {
        __syncthreads();
        *(half8_t*)&As[arow * 72 + acolf] = ah;
        for (int i = 0; i < 4; i++)
            *(half8_t*)&Ws[wrow * 72 + wcol + i * 8] = wv[i];
        __syncthreads();

        bool more = (kb + 64) < 512;
        if (more) {
            const float* ap = aptr + kb + 64;
            const _Float16* wp = wptr + kb + 64;
            a0 = ((const float4*)ap)[0];
            a1 = ((const float4*)ap)[1];
            for (int i = 0; i < 4; i++) wv[i] = *(const half8_t*)(wp + i * 8);
        }

        half8_t af[2], bf[4][2];
        for (int kc = 0; kc < 2; kc++)
            af[kc] = *(const half8_t*)&As[(wm + l16) * 72 + kc * 32 + quad * 8];
        for (int nt = 0; nt < 4; nt++)
            for (int kc = 0; kc < 2; kc++)
                bf[nt][kc] = *(const half8_t*)&Ws[(wn + nt * 16 + l16) * 72 +
                                                  kc * 32 + quad * 8];
        for (int nt = 0; nt < 4; nt++)
            for (int kc = 0; kc < 2; kc++)
                acc[nt] = MFMA16(af[kc], bf[nt][kc], acc[nt]);

        if (more) {
            ah[0] = (_Float16)a0.x; ah[1] = (_Float16)a0.y;
            ah[2] = (_Float16)a0.z; ah[3] = (_Float16)a0.w;
            ah[4] = (_Float16)a1.x; ah[5] = (_Float16)a1.y;
            ah[6] = (_Float16)a1.z; ah[7] = (_Float16)a1.w;
        }
    }
    __syncthreads();

    float scale = (y == 0) ? SCALE_Q : 1.0f;
    if (y < 2) {
        // row-major [s][d] tile: smem[32][136]
        for (int nt = 0; nt < 4; nt++) {
            int d = wn + nt * 16 + l16;
            float b = bias[d];
            for (int r = 0; r < 4; r++)
                smem[(wm + quad * 4 + r) * 136 + d] =
                    (_Float16)((acc[nt][r] + b) * scale);
        }
        __syncthreads();
        int orow = tid >> 3, ocol = (tid & 7) * 16;
        _Float16* outp =
            ((y == 0) ? qbuf : kbuf) + (size_t)(row0 + orow) * 128 + ocol;
        *(half8_t*)(outp)     = *(const half8_t*)&smem[orow * 136 + ocol];
        *(half8_t*)(outp + 8) = *(const half8_t*)&smem[orow * 136 + ocol + 8];
    } else {
        // transposed [d][s] tile: smem[128][40]
        for (int nt = 0; nt < 4; nt++) {
            int d = wn + nt * 16 + l16;
            float b = bias[d];
            half4_t pk;
            for (int r = 0; r < 4; r++) pk[r] = (_Float16)(acc[nt][r] + b);
            *(half4_t*)&smem[d * 40 + wm + quad * 4] = pk;
        }
        __syncthreads();
        int drow = tid >> 1, scol = (tid & 1) * 16;
        int bbn = row0 >> 11, s0 = row0 & 2047;
        _Float16* outp = vtbuf + ((size_t)bbn * 128 + drow) * 2048 + s0 + scol;
        *(half8_t*)(outp)     = *(const half8_t*)&smem[drow * 40 + scol];
        *(half8_t*)(outp + 8) = *(const half8_t*)&smem[drow * 40 + scol + 8];
    }
}

// ---------------------------------------------------------------------------
// Kernel 2: flash attention, split-KV x4.  1024 blocks, 4 waves x 16 q.
// Each block: 64 q rows x 512 keys -> normalized partial O (fp16) + (m,l).
// ---------------------------------------------------------------------------
__global__ __launch_bounds__(256, 3) void attn_kernel(
    const _Float16* __restrict__ qbuf, const _Float16* __restrict__ kbuf,
    const _Float16* __restrict__ vtbuf, _Float16* __restrict__ o_part,
    float2* __restrict__ ml) {
    int bid = blockIdx.x;
    int sp = bid & 3;
    int qt = (bid >> 2) & 31;
    int bb = bid >> 7;
    int q0 = qt * 64;
    int kv0 = sp * 512;
    int tid = threadIdx.x, w = tid >> 6, lane = tid & 63;
    int quad = lane >> 4, l16 = lane & 15;

    __shared__ _Float16 smem[13312];          // 26.6 KB
    _Float16* Ks = smem;                      // [64][136]
    _Float16* Pt = smem + 8704 + w * 1152;    // per-wave [16][72]

    const _Float16* kbase = kbuf + (size_t)bb * 2048 * 128;
    const _Float16* vbase = vtbuf + (size_t)bb * 128 * 2048;

    // Q fragments (B operand): n=l16 -> q row = q0+w*16+l16, k=quad*8+j
    half8_t qf[4];
    {
        const _Float16* qp =
            qbuf + ((size_t)bb * 2048 + q0 + w * 16 + l16) * 128 + quad * 8;
        for (int kc = 0; kc < 4; kc++)
            qf[kc] = *(const half8_t*)(qp + kc * 32);
    }

    // K staging: 64 keys x 128 d; 256 threads -> 32 halfs each
    int krow = tid >> 2, kcol = (tid & 3) * 32;
    const _Float16* kst = kbase + (size_t)(kv0 + krow) * 128 + kcol;
    half8_t kr[4];
    for (int i = 0; i < 4; i++) kr[i] = *(const half8_t*)(kst + i * 8);

    f32x4 o[8] = {};
    float m = -INFINITY, l = 0.0f;

    for (int kv = kv0; kv < kv0 + 512; kv += 64) {
        __syncthreads();
        for (int i = 0; i < 4; i++)
            *(half8_t*)&Ks[krow * 136 + kcol + i * 8] = kr[i];
        __syncthreads();
        if (kv + 64 < kv0 + 512) {
            const _Float16* kp = kst + (size_t)(kv - kv0 + 64) * 128;
            for (int i = 0; i < 4; i++) kr[i] = *(const half8_t*)(kp + i * 8);
        }

        // S^T[key][q] = K Q^T : A = K rows (m=key), B = Q (n=q)
        f32x4 sf[4];
        for (int kt = 0; kt < 4; kt++) {
            f32x4 a = {0.f, 0.f, 0.f, 0.f};
            for (int kc = 0; kc < 4; kc++) {
                half8_t kf = *(const half8_t*)&Ks[(kt * 16 + l16) * 136 +
                                                  kc * 32 + quad * 8];
                a = MFMA16(kf, qf[kc], a);
            }
            sf[kt] = a;
        }

        // issue V loads early (cover L2 latency with softmax VALU work)
        half8_t vv[8][2];
        {
            const _Float16* vp = vbase + (size_t)l16 * 2048 + kv + quad * 8;
            for (int dt = 0; dt < 8; dt++) {
                const _Float16* vpd = vp + (size_t)dt * 16 * 2048;
                vv[dt][0] = *(const half8_t*)(vpd);
                vv[dt][1] = *(const half8_t*)(vpd + 32);
            }
        }

        // online softmax per q=l16; this lane's keys = kt*16 + quad*4 + r
        float mx = m;
        for (int kt = 0; kt < 4; kt++)
            for (int r = 0; r < 4; r++) mx = fmaxf(mx, sf[kt][r]);
        mx = fmaxf(mx, __shfl_xor(mx, 16, 64));
        mx = fmaxf(mx, __shfl_xor(mx, 32, 64));
        float alpha = exp2f(m - mx);
        float rs = 0.0f;
        for (int kt = 0; kt < 4; kt++) {
            half4_t pk;
            for (int r = 0; r < 4; r++) {
                float p = exp2f(sf[kt][r] - mx);
                rs += p;
                pk[r] = (_Float16)p;
            }
            *(half4_t*)&Pt[l16 * 72 + kt * 16 + quad * 4] = pk;
        }
        rs += __shfl_xor(rs, 16, 64);
        rs += __shfl_xor(rs, 32, 64);
        l = l * alpha + rs;
        m = mx;

        // rescale O: alpha of q-row quad*4+r lives at lane quad*4+r
        float ar0 = __shfl(alpha, quad * 4 + 0, 64);
        float ar1 = __shfl(alpha, quad * 4 + 1, 64);
        float ar2 = __shfl(alpha, quad * 4 + 2, 64);
        float ar3 = __shfl(alpha, quad * 4 + 3, 64);
        for (int t = 0; t < 8; t++) {
            o[t][0] *= ar0; o[t][1] *= ar1;
            o[t][2] *= ar2; o[t][3] *= ar3;
        }

        // O += P V
        half8_t pa0 = *(const half8_t*)&Pt[l16 * 72 + quad * 8];
        half8_t pa1 = *(const half8_t*)&Pt[l16 * 72 + 32 + quad * 8];
        for (int dt = 0; dt < 8; dt++) {
            o[dt] = MFMA16(pa0, vv[dt][0], o[dt]);
            o[dt] = MFMA16(pa1, vv[dt][1], o[dt]);
        }
    }

    // epilogue: normalized partial -> o_part (fp16, via LDS), (m,l) -> ml
    float li0 = 1.0f / __shfl(l, quad * 4 + 0, 64);
    float li1 = 1.0f / __shfl(l, quad * 4 + 1, 64);
    float li2 = 1.0f / __shfl(l, quad * 4 + 2, 64);
    float li3 = 1.0f / __shfl(l, quad * 4 + 3, 64);
    __syncthreads();
    for (int dt = 0; dt < 8; dt++) {
        int d = dt * 16 + l16;
        int rr = (w * 16 + quad * 4) * 136 + d;
        Ks[rr]           = (_Float16)(o[dt][0] * li0);
        Ks[rr + 136]     = (_Float16)(o[dt][1] * li1);
        Ks[rr + 272]     = (_Float16)(o[dt][2] * li2);
        Ks[rr + 408]     = (_Float16)(o[dt][3] * li3);
    }
    if (lane < 16)
        ml[(size_t)sp * 16384 + bb * 2048 + q0 + w * 16 + lane] =
            make_float2(m, l);
    __syncthreads();
    int row = tid >> 2, col = (tid & 3) * 32;
    _Float16* op =
        o_part + ((size_t)sp * 16384 + bb * 2048 + q0 + row) * 128 + col;
    for (int i = 0; i < 4; i++)
        *(half8_t*)(op + i * 8) = *(const half8_t*)&Ks[row * 136 + col + i * 8];
}

// ---------------------------------------------------------------------------
// Kernel 3: combine 4 split-KV partials.  1024 blocks x 256 thr, 16 rows/blk.
// ---------------------------------------------------------------------------
__global__ __launch_bounds__(256) void comb_kernel(
    const _Float16* __restrict__ o_part, const float2* __restrict__ ml,
    float* __restrict__ out) {
    int tid = threadIdx.x;
    int row = blockIdx.x * 16 + (tid >> 4);
    int d0 = (tid & 15) * 8;

    float2 s0 = ml[row];
    float2 s1 = ml[16384 + row];
    float2 s2 = ml[32768 + row];
    float2 s3 = ml[49152 + row];
    float M = fmaxf(fmaxf(s0.x, s1.x), fmaxf(s2.x, s3.x));
    float w0 = s0.y * exp2f(s0.x - M);
    float w1 = s1.y * exp2f(s1.x - M);
    float w2 = s2.y * exp2f(s2.x - M);
    float w3 = s3.y * exp2f(s3.x - M);
    float inv = 1.0f / (w0 + w1 + w2 + w3);
    w0 *= inv; w1 *= inv; w2 *= inv; w3 *= inv;

    size_t base = (size_t)row * 128 + d0;
    half8_t h0 = *(const half8_t*)&o_part[base];
    half8_t h1 = *(const half8_t*)&o_part[(size_t)16384 * 128 + base];
    half8_t h2 = *(const half8_t*)&o_part[(size_t)32768 * 128 + base];
    half8_t h3 = *(const half8_t*)&o_part[(size_t)49152 * 128 + base];

    float4 lo, hi;
    lo.x = w0 * (float)h0[0] + w1 * (float)h1[0] + w2 * (float)h2[0] + w3 * (float)h3[0];
    lo.y = w0 * (float)h0[1] + w1 * (float)h1[1] + w2 * (float)h2[1] + w3 * (float)h3[1];
    lo.z = w0 * (float)h0[2] + w1 * (float)h1[2] + w2 * (float)h2[2] + w3 * (float)h3[2];
    lo.w = w0 * (float)h0[3] + w1 * (float)h1[3] + w2 * (float)h2[3] + w3 * (float)h3[3];
    hi.x = w0 * (float)h0[4] + w1 * (float)h1[4] + w2 * (float)h2[4] + w3 * (float)h3[4];
    hi.y = w0 * (float)h0[5] + w1 * (float)h1[5] + w2 * (float)h2[5] + w3 * (float)h3[5];
    hi.z = w0 * (float)h0[6] + w1 * (float)h1[6] + w2 * (float)h2[6] + w3 * (float)h3[6];
    hi.w = w0 * (float)h0[7] + w1 * (float)h1[7] + w2 * (float)h2[7] + w3 * (float)h3[7];
    *(float4*)&out[base]     = lo;
    *(float4*)&out[base + 4] = hi;
}

// ---------------------------------------------------------------------------
extern "C" void kernel_launch(void* const* d_in, const int* in_sizes, int n_in,
                              void* d_out, int out_size, void* d_ws,
                              size_t ws_size, hipStream_t stream) {
    const float* q_in = (const float*)d_in[0];
    const float* k_in = (const float*)d_in[1];
    const float* v_in = (const float*)d_in[2];
    const float* Wq = (const float*)d_in[3];
    const float* Wk = (const float*)d_in[4];
    const float* Wv = (const float*)d_in[5];
    const float* bq = (const float*)d_in[6];
    const float* bk = (const float*)d_in[7];
    const float* bv = (const float*)d_in[8];
    float* out = (float*)d_out;

    char* ws = (char*)d_ws;
    _Float16* WtAll  = (_Float16*)ws;                    // 384 KB
    _Float16* qbuf   = (_Float16*)(ws + 393216);         // 4 MB
    _Float16* kbuf   = (_Float16*)(ws + 4587520);        // 4 MB
    _Float16* vtbuf  = (_Float16*)(ws + 8781824);        // 4 MB
    _Float16* o_part = (_Float16*)(ws + 12976128);       // 16 MB
    float2*   ml     = (float2*)(ws + 29753344);         // 512 KB

    wt_kernel<<<dim3(256, 3), 256, 0, stream>>>(Wq, Wk, Wv, WtAll);
    proj_kernel<<<dim3(512, 3), 256, 0, stream>>>(q_in, k_in, v_in, WtAll, bq,
                                                  bk, bv, qbuf, kbuf, vtbuf);
    attn_kernel<<<dim3(1024), 256, 0, stream>>>(qbuf, kbuf, vtbuf, o_part, ml);
    comb_kernel<<<dim3(1024), 256, 0, stream>>>(o_part, ml, out);
}